// Round 4
// baseline (24251.884 us; speedup 1.0000x reference)
//
#include <hip/hip_runtime.h>
#include <math.h>

// Problem constants
#define B 2048
#define T 128
#define H 512
#define NC 3
#define NO 5
#define G3H 1536   // 3*H
#define BH ((size_t)B * H)

typedef _Float16 half8 __attribute__((ext_vector_type(8)));
typedef float float4v __attribute__((ext_vector_type(4)));

#define LO_SCALE 1024.0f
#define INV_LO (1.0f / 1024.0f)
#define F16_MIN_NORM 6.103515625e-05f

__device__ __forceinline__ float sigmoidf_(float x) {
    return 1.0f / (1.0f + __expf(-x));
}

// Split fp32 -> (hi, lo*1024) f16 pair; hi zeroed in subnormal range (flush safety).
__device__ __forceinline__ void split_f16(float a, _Float16* hi, _Float16* lo) {
    _Float16 h = (_Float16)a;
    if (fabsf(a) < F16_MIN_NORM) h = (_Float16)0.0f;
    *hi = h;
    *lo = (_Float16)((a - (float)h) * LO_SCALE);
}

__device__ __forceinline__ void stage16(const _Float16* gp, _Float16* lp) {
    __builtin_amdgcn_global_load_lds(
        (const __attribute__((address_space(1))) unsigned int*)gp,
        (__attribute__((address_space(3))) unsigned int*)lp,
        16, 0, 0);
}

// ---------------- prep kernels ----------------
__global__ void conv3_kernel(const float* __restrict__ w1, const float* __restrict__ w2,
                             const float* __restrict__ w3,
                             _Float16* o1h, _Float16* o1l, _Float16* o2h, _Float16* o2l,
                             _Float16* o3h, _Float16* o3l) {
    int i = blockIdx.x * 256 + threadIdx.x;
    if (i < G3H * H) {
        split_f16(w1[i], &o1h[i], &o1l[i]);
        split_f16(w2[i], &o2h[i], &o2l[i]);
        split_f16(w3[i], &o3h[i], &o3l[i]);
    }
}

__global__ void prep_kernel(const float* __restrict__ h01, const float* __restrict__ h02,
                            _Float16* h1h, _Float16* h1l, _Float16* h2h, _Float16* h2l) {
    int i = blockIdx.x * 256 + threadIdx.x;
    if (i < B * H) {
        split_f16(h01[i], &h1h[i], &h1l[i]);
        split_f16(h02[i], &h2h[i], &h2l[i]);
    }
}

// ---------------- persistent full-rollout kernel ----------------
// 256 blocks x 256 threads, 1 block/CU (LDS-bound). bid&7 -> n-tile (XCD-local W),
// bid>>3 -> m-tile. Two grid barriers per step.
__global__ __launch_bounds__(256, 1) void gru_persist_kernel(
    const _Float16* __restrict__ wh1h, const _Float16* __restrict__ wh1l,
    const _Float16* __restrict__ wi2h, const _Float16* __restrict__ wi2l,
    const _Float16* __restrict__ wh2h, const _Float16* __restrict__ wh2l,
    const float* __restrict__ W_ih1,   // 3H x 8 fp32
    const float* __restrict__ W_out,   // NO x H fp32
    const float* __restrict__ b_out,
    const float* __restrict__ b_ih1, const float* __restrict__ b_hh1,
    const float* __restrict__ b_ih2, const float* __restrict__ b_hh2,
    const float* __restrict__ cmds,    // T x B x NC
    const float* __restrict__ y0,      // B x NO
    _Float16* __restrict__ h1h, _Float16* __restrict__ h1l,   // slot s at +s*BH
    _Float16* __restrict__ h2h, _Float16* __restrict__ h2l,
    float* __restrict__ out,           // B x T x NO
    unsigned int* __restrict__ bar)
{
    __shared__ _Float16 sAh[2][4096], sAl[2][4096];     // [buf][m64][k64]
    __shared__ _Float16 sWh[2][12288], sWl[2][12288];   // [buf][g3*n64][k64]
    __shared__ float sX[64 * 8];          // x = [y, cmd] per m-row
    __shared__ float sWi1[3][8][64];      // W_ih1 n-slice, [g][k][n]
    __shared__ float sBi1[3][64], sBh1[3][64], sBi2[3][64], sBh2[3][64];
    __shared__ float sWout[5 * 512];
    __shared__ float sBout[5];

    const int tid = threadIdx.x;
    const int wv = tid >> 6, lane = tid & 63;
    const int wm = wv >> 1, wn = wv & 1;
    const int ln = lane & 15, qd = lane >> 4;
    const int bid = blockIdx.x;
    const int n0 = (bid & 7) * 64;
    const int m0 = (bid >> 3) * 64;

    // ---- one-time LDS fills ----
    for (int i = tid; i < 3 * 64 * 8; i += 256) {
        const int g = i >> 9, rem = i & 511, n = rem >> 3, k = rem & 7;
        sWi1[g][k][n] = W_ih1[(g * H + n0 + n) * 8 + k];
    }
    for (int i = tid; i < 192; i += 256) {
        const int g = i >> 6, n = i & 63;
        sBi1[g][n] = b_ih1[g * H + n0 + n];
        sBh1[g][n] = b_hh1[g * H + n0 + n];
        sBi2[g][n] = b_ih2[g * H + n0 + n];
        sBh2[g][n] = b_hh2[g * H + n0 + n];
    }
    for (int i = tid; i < 5 * 512; i += 256) sWout[i] = W_out[i];
    if (tid < 5) sBout[tid] = b_out[tid];

    unsigned int bar_t = 0;
    auto gbar = [&]() {
        __threadfence();
        __syncthreads();
        bar_t += 256;
        if (tid == 0) {
            __hip_atomic_fetch_add(bar, 1u, __ATOMIC_ACQ_REL, __HIP_MEMORY_SCOPE_AGENT);
            while (__hip_atomic_load(bar, __ATOMIC_ACQUIRE, __HIP_MEMORY_SCOPE_AGENT) < bar_t)
                __builtin_amdgcn_s_sleep(8);
        }
        __syncthreads();
        __threadfence();
    };

    auto stage_tile = [&](const _Float16* Ahp, const _Float16* Alp,
                          const _Float16* Whp, const _Float16* Wlp,
                          int k0, int buf) {
        #pragma unroll
        for (int j = 0; j < 2; ++j) {
            const int cid = wv * 128 + j * 64 + lane;
            const int m = cid >> 3, kc = cid & 7;
            const size_t off = (size_t)(m0 + m) * H + k0 + kc * 8;
            stage16(Ahp + off, &sAh[buf][(wv * 128 + j * 64) * 8]);
            stage16(Alp + off, &sAl[buf][(wv * 128 + j * 64) * 8]);
        }
        #pragma unroll
        for (int j = 0; j < 6; ++j) {
            const int cid = wv * 384 + j * 64 + lane;
            const int gg = cid >> 9, rem = cid & 511;
            const int nr = rem >> 3, kc = rem & 7;
            const size_t off = (size_t)(gg * H + n0 + nr) * H + k0 + kc * 8;
            stage16(Whp + off, &sWh[buf][(wv * 384 + j * 64) * 8]);
            stage16(Wlp + off, &sWl[buf][(wv * 384 + j * 64) * 8]);
        }
    };

    float4v accH[4][2][2], accL[4][2][2];
    auto zero_acc = [&]() {
        #pragma unroll
        for (int s = 0; s < 4; ++s)
            #pragma unroll
            for (int a = 0; a < 2; ++a)
                #pragma unroll
                for (int b = 0; b < 2; ++b) {
                    accH[s][a][b] = (float4v)(0.f);
                    accL[s][a][b] = (float4v)(0.f);
                }
    };

    auto compute_tile = [&](int buf, const int sN) {
        #pragma unroll
        for (int ks = 0; ks < 2; ++ks) {
            half8 afh[2], afl[2];
            #pragma unroll
            for (int mt = 0; mt < 2; ++mt) {
                const int ai = (wm * 32 + mt * 16 + ln) * 64 + ks * 32 + qd * 8;
                afh[mt] = *(const half8*)&sAh[buf][ai];
                afl[mt] = *(const half8*)&sAl[buf][ai];
            }
            #pragma unroll
            for (int g = 0; g < 3; ++g) {
                const int s = (g < 2) ? g : sN;
                #pragma unroll
                for (int nt = 0; nt < 2; ++nt) {
                    const int wi = (g * 64 + wn * 32 + nt * 16 + ln) * 64 + ks * 32 + qd * 8;
                    half8 bh = *(const half8*)&sWh[buf][wi];
                    half8 bl = *(const half8*)&sWl[buf][wi];
                    #pragma unroll
                    for (int mt = 0; mt < 2; ++mt) {
                        accH[s][mt][nt] = __builtin_amdgcn_mfma_f32_16x16x32_f16(afh[mt], bh, accH[s][mt][nt], 0, 0, 0);
                        accL[s][mt][nt] = __builtin_amdgcn_mfma_f32_16x16x32_f16(afh[mt], bl, accL[s][mt][nt], 0, 0, 0);
                        accL[s][mt][nt] = __builtin_amdgcn_mfma_f32_16x16x32_f16(afl[mt], bh, accL[s][mt][nt], 0, 0, 0);
                    }
                }
            }
        }
    };

    // y = h2_row . Wout^T + bout for this block's m-rows; lanes p=tid&3 split K.
    auto compute_y = [&](const _Float16* hh_, const _Float16* hl_, float* y5) {
        const int r = tid >> 2, p = tid & 3;
        float a0 = 0, a1 = 0, a2 = 0, a3 = 0, a4 = 0;
        const size_t base = (size_t)(m0 + r) * H + p * 128;
        for (int kk = 0; kk < 128; kk += 8) {
            half8 hh8 = *(const half8*)(hh_ + base + kk);
            half8 hl8 = *(const half8*)(hl_ + base + kk);
            #pragma unroll
            for (int j = 0; j < 8; ++j) {
                const float hv = (float)hh8[j] + (float)hl8[j] * INV_LO;
                const int k = p * 128 + kk + j;
                a0 = fmaf(hv, sWout[0 * 512 + k], a0);
                a1 = fmaf(hv, sWout[1 * 512 + k], a1);
                a2 = fmaf(hv, sWout[2 * 512 + k], a2);
                a3 = fmaf(hv, sWout[3 * 512 + k], a3);
                a4 = fmaf(hv, sWout[4 * 512 + k], a4);
            }
        }
        a0 += __shfl_xor(a0, 1, 64); a0 += __shfl_xor(a0, 2, 64);
        a1 += __shfl_xor(a1, 1, 64); a1 += __shfl_xor(a1, 2, 64);
        a2 += __shfl_xor(a2, 1, 64); a2 += __shfl_xor(a2, 2, 64);
        a3 += __shfl_xor(a3, 1, 64); a3 += __shfl_xor(a3, 2, 64);
        a4 += __shfl_xor(a4, 1, 64); a4 += __shfl_xor(a4, 2, 64);
        y5[0] = a0 + sBout[0]; y5[1] = a1 + sBout[1]; y5[2] = a2 + sBout[2];
        y5[3] = a3 + sBout[3]; y5[4] = a4 + sBout[4];
    };

    int si = 0;
    for (int t = 0; t < T; ++t) {
        const _Float16* h1ph = h1h + (size_t)si * BH;
        const _Float16* h1pl = h1l + (size_t)si * BH;
        const _Float16* h2ph = h2h + (size_t)si * BH;
        const _Float16* h2pl = h2l + (size_t)si * BH;
        _Float16* h1nh = h1h + (size_t)(si ^ 1) * BH;
        _Float16* h1nl = h1l + (size_t)(si ^ 1) * BH;
        _Float16* h2nh = h2h + (size_t)(si ^ 1) * BH;
        _Float16* h2nl = h2l + (size_t)(si ^ 1) * BH;

        // ================= phase A: layer 1 =================
        zero_acc();
        stage_tile(h1ph, h1pl, wh1h, wh1l, 0, 0);   // async; overlaps y-compute

        // build sX = [y_{t-1}, cmd_t]
        if (t == 0) {
            if (tid < 64) {
                #pragma unroll
                for (int o2 = 0; o2 < NO; ++o2)
                    sX[tid * 8 + o2] = y0[(size_t)(m0 + tid) * NO + o2];
                #pragma unroll
                for (int c = 0; c < NC; ++c)
                    sX[tid * 8 + NO + c] = cmds[(size_t)(m0 + tid) * NC + c];
            }
        } else {
            float y5[5];
            compute_y(h2ph, h2pl, y5);
            const int r = tid >> 2, p = tid & 3;
            if (p == 0) {
                #pragma unroll
                for (int o2 = 0; o2 < NO; ++o2) sX[r * 8 + o2] = y5[o2];
                if (n0 == 0) {
                    #pragma unroll
                    for (int o2 = 0; o2 < NO; ++o2)
                        out[(size_t)(m0 + r) * (T * NO) + (size_t)(t - 1) * NO + o2] = y5[o2];
                }
            }
            if (tid < 64) {
                #pragma unroll
                for (int c = 0; c < NC; ++c)
                    sX[tid * 8 + NO + c] = cmds[(size_t)t * B * NC + (size_t)(m0 + tid) * NC + c];
            }
        }

        // hidden path: 8 K-tiles of h1_prev @ W_hh1^T (n-gate -> set 3)
        for (int it = 0; it < 8; ++it) {
            const int buf = it & 1;
            __syncthreads();
            if (it + 1 < 8) stage_tile(h1ph, h1pl, wh1h, wh1l, (it + 1) * 64, buf ^ 1);
            compute_tile(buf, 3);
        }

        // epilogue layer 1
        #pragma unroll
        for (int nt = 0; nt < 2; ++nt) {
            const int gnl = wn * 32 + nt * 16 + ln;
            const int gn = n0 + gnl;
            #pragma unroll
            for (int mt = 0; mt < 2; ++mt) {
                #pragma unroll
                for (int r = 0; r < 4; ++r) {
                    const int mloc = wm * 32 + mt * 16 + qd * 4 + r;
                    const int m = m0 + mloc;
                    float giR = sBi1[0][gnl], giZ = sBi1[1][gnl], giN = sBi1[2][gnl];
                    #pragma unroll
                    for (int k = 0; k < 8; ++k) {
                        const float xv = sX[mloc * 8 + k];
                        giR = fmaf(xv, sWi1[0][k][gnl], giR);
                        giZ = fmaf(xv, sWi1[1][k][gnl], giZ);
                        giN = fmaf(xv, sWi1[2][k][gnl], giN);
                    }
                    const float gR = giR + sBh1[0][gnl] + accH[0][mt][nt][r] + accL[0][mt][nt][r] * INV_LO;
                    const float gZ = giZ + sBh1[1][gnl] + accH[1][mt][nt][r] + accL[1][mt][nt][r] * INV_LO;
                    const float gNh = sBh1[2][gnl] + accH[3][mt][nt][r] + accL[3][mt][nt][r] * INV_LO;
                    const float R = sigmoidf_(gR), Z = sigmoidf_(gZ);
                    const float N = tanhf(fmaf(R, gNh, giN));
                    const size_t idx = (size_t)m * H + gn;
                    const float hp = (float)h1ph[idx] + (float)h1pl[idx] * INV_LO;
                    const float hv = (1.f - Z) * N + Z * hp;
                    split_f16(hv, &h1nh[idx], &h1nl[idx]);
                }
            }
        }
        gbar();

        // ================= phase B: layer 2 =================
        zero_acc();
        stage_tile(h1nh, h1nl, wi2h, wi2l, 0, 0);
        for (int it = 0; it < 16; ++it) {
            const int buf = it & 1;
            __syncthreads();
            if (it + 1 < 16) {
                if (it + 1 < 8)
                    stage_tile(h1nh, h1nl, wi2h, wi2l, (it + 1) * 64, buf ^ 1);
                else
                    stage_tile(h2ph, h2pl, wh2h, wh2l, ((it + 1) & 7) * 64, buf ^ 1);
            }
            if (it < 8) compute_tile(buf, 2);
            else        compute_tile(buf, 3);
        }

        // epilogue layer 2
        #pragma unroll
        for (int nt = 0; nt < 2; ++nt) {
            const int gnl = wn * 32 + nt * 16 + ln;
            const int gn = n0 + gnl;
            #pragma unroll
            for (int mt = 0; mt < 2; ++mt) {
                #pragma unroll
                for (int r = 0; r < 4; ++r) {
                    const int m = m0 + wm * 32 + mt * 16 + qd * 4 + r;
                    const float gR = sBi2[0][gnl] + sBh2[0][gnl]
                        + accH[0][mt][nt][r] + accL[0][mt][nt][r] * INV_LO;
                    const float gZ = sBi2[1][gnl] + sBh2[1][gnl]
                        + accH[1][mt][nt][r] + accL[1][mt][nt][r] * INV_LO;
                    const float gNi = sBi2[2][gnl] + accH[2][mt][nt][r] + accL[2][mt][nt][r] * INV_LO;
                    const float gNh = sBh2[2][gnl] + accH[3][mt][nt][r] + accL[3][mt][nt][r] * INV_LO;
                    const float R = sigmoidf_(gR), Z = sigmoidf_(gZ);
                    const float N = tanhf(fmaf(R, gNh, gNi));
                    const size_t idx = (size_t)m * H + gn;
                    const float hp = (float)h2ph[idx] + (float)h2pl[idx] * INV_LO;
                    const float hv = (1.f - Z) * N + Z * hp;
                    split_f16(hv, &h2nh[idx], &h2nl[idx]);
                }
            }
        }
        gbar();
        si ^= 1;
    }

    // final y_{T-1} from last h2
    {
        float y5[5];
        compute_y(h2h + (size_t)si * BH, h2l + (size_t)si * BH, y5);
        const int r = tid >> 2, p = tid & 3;
        if (p == 0 && n0 == 0) {
            #pragma unroll
            for (int o2 = 0; o2 < NO; ++o2)
                out[(size_t)(m0 + r) * (T * NO) + (size_t)(T - 1) * NO + o2] = y5[o2];
        }
    }
}

extern "C" void kernel_launch(void* const* d_in, const int* in_sizes, int n_in,
                              void* d_out, int out_size, void* d_ws, size_t ws_size,
                              hipStream_t stream) {
    (void)in_sizes; (void)n_in; (void)out_size; (void)ws_size;
    const float* cmds  = (const float*)d_in[1];
    const float* y0    = (const float*)d_in[2];
    const float* h01   = (const float*)d_in[3];
    const float* h02   = (const float*)d_in[4];
    const float* W_ih1 = (const float*)d_in[5];
    const float* W_hh1 = (const float*)d_in[6];
    const float* b_ih1 = (const float*)d_in[7];
    const float* b_hh1 = (const float*)d_in[8];
    const float* W_ih2 = (const float*)d_in[9];
    const float* W_hh2 = (const float*)d_in[10];
    const float* b_ih2 = (const float*)d_in[11];
    const float* b_hh2 = (const float*)d_in[12];
    const float* W_out = (const float*)d_in[13];
    const float* b_out = (const float*)d_in[14];
    float* out = (float*)d_out;

    // ---- workspace layout (~26.2 MB) ----
    char* ws = (char*)d_ws;
    size_t o = 0;
    const size_t WSZ = (size_t)G3H * H * sizeof(_Float16);
    _Float16* wh1h = (_Float16*)(ws + o); o += WSZ;
    _Float16* wh1l = (_Float16*)(ws + o); o += WSZ;
    _Float16* wi2h = (_Float16*)(ws + o); o += WSZ;
    _Float16* wi2l = (_Float16*)(ws + o); o += WSZ;
    _Float16* wh2h = (_Float16*)(ws + o); o += WSZ;
    _Float16* wh2l = (_Float16*)(ws + o); o += WSZ;
    _Float16* h1hs = (_Float16*)(ws + o); o += 2 * BH * sizeof(_Float16);
    _Float16* h1ls = (_Float16*)(ws + o); o += 2 * BH * sizeof(_Float16);
    _Float16* h2hs = (_Float16*)(ws + o); o += 2 * BH * sizeof(_Float16);
    _Float16* h2ls = (_Float16*)(ws + o); o += 2 * BH * sizeof(_Float16);
    unsigned int* bar = (unsigned int*)(ws + o); o += 256;

    hipMemsetAsync(bar, 0, sizeof(unsigned int), stream);
    conv3_kernel<<<(G3H * H + 255) / 256, 256, 0, stream>>>(
        W_hh1, W_ih2, W_hh2, wh1h, wh1l, wi2h, wi2l, wh2h, wh2l);
    prep_kernel<<<(B * H + 255) / 256, 256, 0, stream>>>(
        h01, h02, h1hs, h1ls, h2hs, h2ls);

    gru_persist_kernel<<<256, 256, 0, stream>>>(
        wh1h, wh1l, wi2h, wi2l, wh2h, wh2l,
        W_ih1, W_out, b_out,
        b_ih1, b_hh1, b_ih2, b_hh2,
        cmds, y0,
        h1hs, h1ls, h2hs, h2ls,
        out, bar);
}

// Round 5
// 11837.489 us; speedup vs baseline: 2.0487x; 2.0487x over previous
//
#include <hip/hip_runtime.h>
#include <math.h>

// Problem constants
#define B 2048
#define T 128
#define H 512
#define NC 3
#define NO 5
#define G3H 1536   // 3*H
#define BHE ((size_t)B * H)

typedef _Float16 half8 __attribute__((ext_vector_type(8)));
typedef float float4v __attribute__((ext_vector_type(4)));

#define LO_SCALE 1024.0f
#define INV_LO (1.0f / 1024.0f)
#define F16_MIN_NORM 6.103515625e-05f

__device__ __forceinline__ float sigmoidf_(float x) {
    return 1.0f / (1.0f + __expf(-x));
}

// Split fp32 -> (hi, lo*1024) f16 pair; hi zeroed in subnormal range (flush safety).
__device__ __forceinline__ void split_f16(float a, _Float16* hi, _Float16* lo) {
    _Float16 h = (_Float16)a;
    if (fabsf(a) < F16_MIN_NORM) h = (_Float16)0.0f;
    *hi = h;
    *lo = (_Float16)((a - (float)h) * LO_SCALE);
}

// Bank-conflict-free swizzle: element (row, k) of a 512-col matrix lives at
// row*512 + swz(row,k). 16B chunk c = (k>>3)&7 goes to slot c ^ (row&7).
// Staging (linear global->LDS copy) preserves this; fragment ds_reads then
// spread 16 lanes over 8 bank-groups (2-way = free) instead of 16-way.
__device__ __forceinline__ int swzk(int row, int k) {
    return (k & ~63) | ((((k >> 3) & 7) ^ (row & 7)) << 3) | (k & 7);
}
__device__ __forceinline__ size_t hidx(int row, int k) {
    return (size_t)row * H + swzk(row, k);
}

// async 16B global->LDS (wave-uniform LDS base; lane lands at base + lane*16B)
__device__ __forceinline__ void stage16(const _Float16* gp, _Float16* lp) {
    __builtin_amdgcn_global_load_lds(
        (const __attribute__((address_space(1))) unsigned int*)gp,
        (__attribute__((address_space(3))) unsigned int*)lp,
        16, 0, 0);
}

// ---------------- prep kernels (once per launch) ----------------

// split + swizzle the three big weight matrices (1536 x 512)
__global__ void conv3_kernel(const float* __restrict__ w1, const float* __restrict__ w2,
                             const float* __restrict__ w3,
                             _Float16* o1h, _Float16* o1l, _Float16* o2h, _Float16* o2l,
                             _Float16* o3h, _Float16* o3l) {
    int i = blockIdx.x * 256 + threadIdx.x;
    if (i < G3H * H) {
        const int r = i >> 9, k = i & 511;
        const size_t d = (size_t)r * H + swzk(r, k);
        split_f16(w1[i], &o1h[d], &o1l[d]);
        split_f16(w2[i], &o2h[d], &o2l[d]);
        split_f16(w3[i], &o3h[d], &o3l[d]);
    }
}

// split + swizzle h0_1 / h0_2 into slot-0 state buffers
__global__ void prep_kernel(const float* __restrict__ h01, const float* __restrict__ h02,
                            _Float16* h1h, _Float16* h1l, _Float16* h2h, _Float16* h2l) {
    int i = blockIdx.x * 256 + threadIdx.x;
    if (i < B * H) {
        const int r = i >> 9, k = i & 511;
        const size_t d = (size_t)r * H + swzk(r, k);
        split_f16(h01[i], &h1h[d], &h1l[d]);
        split_f16(h02[i], &h2h[d], &h2l[d]);
    }
}

// ---------------- shared GEMM helpers ----------------

// stage one 64x64 K-tile: A (hi/lo, 16KB) + 3-gate W (hi/lo, 48KB)
__device__ __forceinline__ void stage_tile(
    const _Float16* __restrict__ Ahp, const _Float16* __restrict__ Alp,
    const _Float16* __restrict__ Whp, const _Float16* __restrict__ Wlp,
    int m0, int n0, int k0, int wv, int lane,
    _Float16* sAh, _Float16* sAl, _Float16* sWh, _Float16* sWl)
{
    #pragma unroll
    for (int j = 0; j < 2; ++j) {
        const int cid = wv * 128 + j * 64 + lane;
        const int m = cid >> 3, kc = cid & 7;
        const size_t off = (size_t)(m0 + m) * H + k0 + kc * 8;
        stage16(Ahp + off, &sAh[(wv * 128 + j * 64) * 8]);
        stage16(Alp + off, &sAl[(wv * 128 + j * 64) * 8]);
    }
    #pragma unroll
    for (int j = 0; j < 6; ++j) {
        const int cid = wv * 384 + j * 64 + lane;
        const int gg = cid >> 9, rem = cid & 511;
        const int nr = rem >> 3, kc = rem & 7;
        const size_t off = (size_t)(gg * H + n0 + nr) * H + k0 + kc * 8;
        stage16(Whp + off, &sWh[(wv * 384 + j * 64) * 8]);
        stage16(Wlp + off, &sWl[(wv * 384 + j * 64) * 8]);
    }
}

// one 64x64x64 tile of 3-gate split-f16 MFMA; sN = acc set for the n-gate
__device__ __forceinline__ void compute_tile(
    const _Float16* sAh, const _Float16* sAl,
    const _Float16* sWh, const _Float16* sWl,
    int wm, int wn, int ln, int qd, int sN,
    float4v (&accH)[4][2][2], float4v (&accL)[4][2][2])
{
    #pragma unroll
    for (int ks = 0; ks < 2; ++ks) {
        const int c = ks * 4 + qd;
        half8 afh[2], afl[2];
        #pragma unroll
        for (int mt = 0; mt < 2; ++mt) {
            const int row = wm * 32 + mt * 16 + ln;
            const int ai = row * 64 + ((c ^ (row & 7)) << 3);
            afh[mt] = *(const half8*)&sAh[ai];
            afl[mt] = *(const half8*)&sAl[ai];
        }
        #pragma unroll
        for (int g = 0; g < 3; ++g) {
            const int s = (g < 2) ? g : sN;
            #pragma unroll
            for (int nt = 0; nt < 2; ++nt) {
                const int nr = wn * 32 + nt * 16 + ln;
                const int wi = (g * 64 + nr) * 64 + ((c ^ (nr & 7)) << 3);
                half8 bh = *(const half8*)&sWh[wi];
                half8 bl = *(const half8*)&sWl[wi];
                #pragma unroll
                for (int mt = 0; mt < 2; ++mt) {
                    accH[s][mt][nt] = __builtin_amdgcn_mfma_f32_16x16x32_f16(afh[mt], bh, accH[s][mt][nt], 0, 0, 0);
                    accL[s][mt][nt] = __builtin_amdgcn_mfma_f32_16x16x32_f16(afh[mt], bl, accL[s][mt][nt], 0, 0, 0);
                    accL[s][mt][nt] = __builtin_amdgcn_mfma_f32_16x16x32_f16(afl[mt], bh, accL[s][mt][nt], 0, 0, 0);
                }
            }
        }
    }
}

// ---------------- layer-1 GRU step ----------------
// gh = h1_prev @ W_hh1^T via MFMA (8 K-tiles); gi = [y,cmd] @ W_ih1^T in the
// fp32 epilogue (K=8). grid (B/64 * H/64) = 256 blocks, 256 thr.
__global__ __launch_bounds__(256, 1) void gru1_kernel(
    const _Float16* __restrict__ Ah, const _Float16* __restrict__ Al,   // h1p swz
    const _Float16* __restrict__ Wh, const _Float16* __restrict__ Wl,   // wh1 swz
    const float* __restrict__ ysrc,    // B x NO fp32 (y0 or ybuf)
    const float* __restrict__ cmd_t,   // B x NC
    const float* __restrict__ W_ih1,   // 3H x 8
    const float* __restrict__ b_ih1, const float* __restrict__ b_hh1,
    _Float16* __restrict__ hnh, _Float16* __restrict__ hnl)
{
    __shared__ _Float16 sAh[2][4096], sAl[2][4096];
    __shared__ _Float16 sWh[2][12288], sWl[2][12288];
    __shared__ float sX[64 * 8];
    __shared__ float sWi1[3][8][64];
    __shared__ float sBi1[3][64], sBh1[3][64];

    const int tid = threadIdx.x;
    const int wv = tid >> 6, lane = tid & 63;
    const int wm = wv >> 1, wn = wv & 1;
    const int ln = lane & 15, qd = lane >> 4;
    const int n0 = (blockIdx.x & 7) * 64;    // XCD-aligned n-tile
    const int m0 = (blockIdx.x >> 3) * 64;

    // one-time LDS fills (visibility via K-loop syncs)
    for (int i = tid; i < 3 * 64 * 8; i += 256) {
        const int g = i >> 9, rem = i & 511, n = rem >> 3, k = rem & 7;
        sWi1[g][k][n] = W_ih1[(g * H + n0 + n) * 8 + k];
    }
    if (tid < 192) {
        const int g = tid >> 6, n = tid & 63;
        sBi1[g][n] = b_ih1[g * H + n0 + n];
        sBh1[g][n] = b_hh1[g * H + n0 + n];
    }
    if (tid < 64) {
        #pragma unroll
        for (int o2 = 0; o2 < NO; ++o2)
            sX[tid * 8 + o2] = ysrc[(size_t)(m0 + tid) * NO + o2];
        #pragma unroll
        for (int c = 0; c < NC; ++c)
            sX[tid * 8 + NO + c] = cmd_t[(size_t)(m0 + tid) * NC + c];
    }

    float4v accH[4][2][2], accL[4][2][2];
    #pragma unroll
    for (int s = 0; s < 4; ++s)
        #pragma unroll
        for (int a = 0; a < 2; ++a)
            #pragma unroll
            for (int b = 0; b < 2; ++b) { accH[s][a][b] = (float4v)(0.f); accL[s][a][b] = (float4v)(0.f); }

    stage_tile(Ah, Al, Wh, Wl, m0, n0, 0, wv, lane,
               sAh[0], sAl[0], sWh[0], sWl[0]);
    for (int it = 0; it < 8; ++it) {
        const int buf = it & 1;
        __syncthreads();
        if (it + 1 < 8)
            stage_tile(Ah, Al, Wh, Wl, m0, n0, (it + 1) * 64, wv, lane,
                       sAh[buf ^ 1], sAl[buf ^ 1], sWh[buf ^ 1], sWl[buf ^ 1]);
        compute_tile(sAh[buf], sAl[buf], sWh[buf], sWl[buf], wm, wn, ln, qd, 3, accH, accL);
    }

    // epilogue: input path (fp32) + gates + blend; C/D: col=ln, row=qd*4+reg
    #pragma unroll
    for (int nt = 0; nt < 2; ++nt) {
        const int gnl = wn * 32 + nt * 16 + ln;
        const int gn = n0 + gnl;
        #pragma unroll
        for (int mt = 0; mt < 2; ++mt) {
            #pragma unroll
            for (int r = 0; r < 4; ++r) {
                const int mloc = wm * 32 + mt * 16 + qd * 4 + r;
                const int m = m0 + mloc;
                float giR = sBi1[0][gnl], giZ = sBi1[1][gnl], giN = sBi1[2][gnl];
                #pragma unroll
                for (int k = 0; k < 8; ++k) {
                    const float xv = sX[mloc * 8 + k];
                    giR = fmaf(xv, sWi1[0][k][gnl], giR);
                    giZ = fmaf(xv, sWi1[1][k][gnl], giZ);
                    giN = fmaf(xv, sWi1[2][k][gnl], giN);
                }
                const float gR = giR + sBh1[0][gnl] + accH[0][mt][nt][r] + accL[0][mt][nt][r] * INV_LO;
                const float gZ = giZ + sBh1[1][gnl] + accH[1][mt][nt][r] + accL[1][mt][nt][r] * INV_LO;
                const float gNh = sBh1[2][gnl] + accH[3][mt][nt][r] + accL[3][mt][nt][r] * INV_LO;
                const float R = sigmoidf_(gR), Z = sigmoidf_(gZ);
                const float N = tanhf(fmaf(R, gNh, giN));
                const size_t idx = hidx(m, gn);
                const float hp = (float)Ah[idx] + (float)Al[idx] * INV_LO;
                const float hv = (1.f - Z) * N + Z * hp;
                split_f16(hv, &hnh[idx], &hnl[idx]);
            }
        }
    }
}

// ---------------- layer-2 GRU step ----------------
// phase 0: gi = h1_cur @ W_ih2^T (8 tiles), phase 1: gh = h2_prev @ W_hh2^T (8)
__global__ __launch_bounds__(256, 1) void gru2_kernel(
    const _Float16* __restrict__ Aih, const _Float16* __restrict__ Ail,  // h1 cur swz
    const _Float16* __restrict__ Wih, const _Float16* __restrict__ Wil,  // wi2 swz
    const _Float16* __restrict__ Ahh, const _Float16* __restrict__ Ahl,  // h2 prev swz
    const _Float16* __restrict__ Whh, const _Float16* __restrict__ Whl,  // wh2 swz
    const float* __restrict__ b_i, const float* __restrict__ b_h,
    _Float16* __restrict__ hnh, _Float16* __restrict__ hnl)
{
    __shared__ _Float16 sAh[2][4096], sAl[2][4096];
    __shared__ _Float16 sWh[2][12288], sWl[2][12288];
    __shared__ float sBi[3][64], sBh[3][64];

    const int tid = threadIdx.x;
    const int wv = tid >> 6, lane = tid & 63;
    const int wm = wv >> 1, wn = wv & 1;
    const int ln = lane & 15, qd = lane >> 4;
    const int n0 = (blockIdx.x & 7) * 64;
    const int m0 = (blockIdx.x >> 3) * 64;

    if (tid < 192) {
        const int g = tid >> 6, n = tid & 63;
        sBi[g][n] = b_i[g * H + n0 + n];
        sBh[g][n] = b_h[g * H + n0 + n];
    }

    float4v accH[4][2][2], accL[4][2][2];
    #pragma unroll
    for (int s = 0; s < 4; ++s)
        #pragma unroll
        for (int a = 0; a < 2; ++a)
            #pragma unroll
            for (int b = 0; b < 2; ++b) { accH[s][a][b] = (float4v)(0.f); accL[s][a][b] = (float4v)(0.f); }

    stage_tile(Aih, Ail, Wih, Wil, m0, n0, 0, wv, lane,
               sAh[0], sAl[0], sWh[0], sWl[0]);
    for (int it = 0; it < 16; ++it) {
        const int buf = it & 1;
        __syncthreads();
        if (it + 1 < 16) {
            if (it + 1 < 8)
                stage_tile(Aih, Ail, Wih, Wil, m0, n0, (it + 1) * 64, wv, lane,
                           sAh[buf ^ 1], sAl[buf ^ 1], sWh[buf ^ 1], sWl[buf ^ 1]);
            else
                stage_tile(Ahh, Ahl, Whh, Whl, m0, n0, ((it + 1) & 7) * 64, wv, lane,
                           sAh[buf ^ 1], sAl[buf ^ 1], sWh[buf ^ 1], sWl[buf ^ 1]);
        }
        compute_tile(sAh[buf], sAl[buf], sWh[buf], sWl[buf],
                     wm, wn, ln, qd, (it < 8) ? 2 : 3, accH, accL);
    }

    #pragma unroll
    for (int nt = 0; nt < 2; ++nt) {
        const int gnl = wn * 32 + nt * 16 + ln;
        const int gn = n0 + gnl;
        #pragma unroll
        for (int mt = 0; mt < 2; ++mt) {
            #pragma unroll
            for (int r = 0; r < 4; ++r) {
                const int m = m0 + wm * 32 + mt * 16 + qd * 4 + r;
                const float gR = sBi[0][gnl] + sBh[0][gnl]
                    + accH[0][mt][nt][r] + accL[0][mt][nt][r] * INV_LO;
                const float gZ = sBi[1][gnl] + sBh[1][gnl]
                    + accH[1][mt][nt][r] + accL[1][mt][nt][r] * INV_LO;
                const float gNi = sBi[2][gnl] + accH[2][mt][nt][r] + accL[2][mt][nt][r] * INV_LO;
                const float gNh = sBh[2][gnl] + accH[3][mt][nt][r] + accL[3][mt][nt][r] * INV_LO;
                const float R = sigmoidf_(gR), Z = sigmoidf_(gZ);
                const float N = tanhf(fmaf(R, gNh, gNi));
                const size_t idx = hidx(m, gn);
                const float hp = (float)Ahh[idx] + (float)Ahl[idx] * INV_LO;
                const float hv = (1.f - Z) * N + Z * hp;
                split_f16(hv, &hnh[idx], &hnl[idx]);
            }
        }
    }
}

// ---------------- output projection ----------------
// one wave per batch row; swizzled h2 row is CONTIGUOUS in slot order, only the
// W_out k-index is permuted. Writes out[b][t][:] and ybuf (next step's y input).
__global__ __launch_bounds__(256) void yout_kernel(
    const _Float16* __restrict__ h2h, const _Float16* __restrict__ h2l,
    const float* __restrict__ Wout, const float* __restrict__ bout,
    float* __restrict__ out, int t,
    float* __restrict__ ybuf)
{
    const int wv = threadIdx.x >> 6, lane = threadIdx.x & 63;
    const int b = blockIdx.x * 4 + wv;
    const size_t hb = (size_t)b * H + lane * 8;
    half8 hh = *(const half8*)(h2h + hb);
    half8 hl = *(const half8*)(h2l + hb);
    const int tl = lane >> 3, cw = lane & 7;
    const int kbase = tl * 64 + ((cw ^ (b & 7)) << 3);
    float hv[8];
    #pragma unroll
    for (int j = 0; j < 8; ++j) hv[j] = (float)hh[j] + (float)hl[j] * INV_LO;
    float acc[NO];
    #pragma unroll
    for (int o = 0; o < NO; ++o) {
        acc[o] = 0.f;
        const float* w = Wout + (size_t)o * H + kbase;
        #pragma unroll
        for (int j = 0; j < 8; ++j) acc[o] = fmaf(hv[j], w[j], acc[o]);
    }
    #pragma unroll
    for (int off = 32; off > 0; off >>= 1)
        #pragma unroll
        for (int o = 0; o < NO; ++o) acc[o] += __shfl_down(acc[o], off, 64);
    if (lane == 0) {
        #pragma unroll
        for (int o = 0; o < NO; ++o) {
            const float y = acc[o] + bout[o];
            out[(size_t)b * (T * NO) + (size_t)t * NO + o] = y;
            ybuf[(size_t)b * NO + o] = y;
        }
    }
}

extern "C" void kernel_launch(void* const* d_in, const int* in_sizes, int n_in,
                              void* d_out, int out_size, void* d_ws, size_t ws_size,
                              hipStream_t stream) {
    (void)in_sizes; (void)n_in; (void)out_size; (void)ws_size;
    const float* cmds  = (const float*)d_in[1];
    const float* y0    = (const float*)d_in[2];
    const float* h01   = (const float*)d_in[3];
    const float* h02   = (const float*)d_in[4];
    const float* W_ih1 = (const float*)d_in[5];
    const float* W_hh1 = (const float*)d_in[6];
    const float* b_ih1 = (const float*)d_in[7];
    const float* b_hh1 = (const float*)d_in[8];
    const float* W_ih2 = (const float*)d_in[9];
    const float* W_hh2 = (const float*)d_in[10];
    const float* b_ih2 = (const float*)d_in[11];
    const float* b_hh2 = (const float*)d_in[12];
    const float* W_out = (const float*)d_in[13];
    const float* b_out = (const float*)d_in[14];
    float* out = (float*)d_out;

    // ---- workspace (~25.5 MB) ----
    char* ws = (char*)d_ws;
    size_t o = 0;
    const size_t WSZ = (size_t)G3H * H * sizeof(_Float16);
    _Float16* wh1h = (_Float16*)(ws + o); o += WSZ;
    _Float16* wh1l = (_Float16*)(ws + o); o += WSZ;
    _Float16* wi2h = (_Float16*)(ws + o); o += WSZ;
    _Float16* wi2l = (_Float16*)(ws + o); o += WSZ;
    _Float16* wh2h = (_Float16*)(ws + o); o += WSZ;
    _Float16* wh2l = (_Float16*)(ws + o); o += WSZ;
    _Float16 *h1h[2], *h1l[2], *h2h[2], *h2l[2];
    for (int i = 0; i < 2; ++i) { h1h[i] = (_Float16*)(ws + o); o += BHE * 2; }
    for (int i = 0; i < 2; ++i) { h1l[i] = (_Float16*)(ws + o); o += BHE * 2; }
    for (int i = 0; i < 2; ++i) { h2h[i] = (_Float16*)(ws + o); o += BHE * 2; }
    for (int i = 0; i < 2; ++i) { h2l[i] = (_Float16*)(ws + o); o += BHE * 2; }
    float* ybuf = (float*)(ws + o); o += (size_t)B * NO * 4;

    conv3_kernel<<<(G3H * H + 255) / 256, 256, 0, stream>>>(
        W_hh1, W_ih2, W_hh2, wh1h, wh1l, wi2h, wi2l, wh2h, wh2l);
    prep_kernel<<<(B * H + 255) / 256, 256, 0, stream>>>(
        h01, h02, h1h[0], h1l[0], h2h[0], h2l[0]);

    for (int t = 0; t < T; ++t) {
        const int si = t & 1, so = si ^ 1;
        const float* ysrc = (t == 0) ? y0 : ybuf;

        gru1_kernel<<<256, 256, 0, stream>>>(
            h1h[si], h1l[si], wh1h, wh1l,
            ysrc, cmds + (size_t)t * B * NC,
            W_ih1, b_ih1, b_hh1,
            h1h[so], h1l[so]);

        gru2_kernel<<<256, 256, 0, stream>>>(
            h1h[so], h1l[so], wi2h, wi2l,
            h2h[si], h2l[si], wh2h, wh2l,
            b_ih2, b_hh2,
            h2h[so], h2l[so]);

        yout_kernel<<<B / 4, 256, 0, stream>>>(
            h2h[so], h2l[so], W_out, b_out, out, t, ybuf);
    }
}